// Round 1
// baseline (605.178 us; speedup 1.0000x reference)
//
#include <hip/hip_runtime.h>

// GNNLayer: B=8, N=200, D=128, fp32 I/O. Recompute-Ce two-pass, bf16 MFMA.
// R3: transposed AhT/VhT for float4 epilogue loads in MODE0, v_cvt_pk_bf16_f32
// fragment conversion, 32KB swizzled Bs (5 blocks/CU), base=Bh+Cb prefolded,
// hpath fused into gemm_pass<1> tail, parallelized stats_final.

#define B_ 8
#define N_ 200
#define D_ 128
#define BN_ (B_*N_)      // 1600
#define HN_ (BN_*D_)     // 204800

typedef __attribute__((ext_vector_type(8))) short short8v;
typedef __attribute__((ext_vector_type(4))) short short4v;
typedef __attribute__((ext_vector_type(4))) float float4v;
typedef __attribute__((ext_vector_type(4))) unsigned int uint4v;

__device__ __forceinline__ unsigned short f2b(float f) {
  unsigned u = __float_as_uint(f);
  u += 0x7FFFu + ((u >> 16) & 1u);
  return (unsigned short)(u >> 16);
}

// packed fp32->bf16 (RNE, identical to f2b) — 4 instrs for 8 elements
__device__ __forceinline__ short8v cvt_bf16x8(float4v lo, float4v hi) {
  unsigned int r0, r1, r2, r3;
  asm("v_cvt_pk_bf16_f32 %0, %1, %2" : "=v"(r0) : "v"(lo.x), "v"(lo.y));
  asm("v_cvt_pk_bf16_f32 %0, %1, %2" : "=v"(r1) : "v"(lo.z), "v"(lo.w));
  asm("v_cvt_pk_bf16_f32 %0, %1, %2" : "=v"(r2) : "v"(hi.x), "v"(hi.y));
  asm("v_cvt_pk_bf16_f32 %0, %1, %2" : "=v"(r3) : "v"(hi.z), "v"(hi.w));
  uint4v u; u.x = r0; u.y = r1; u.z = r2; u.w = r3;
  return __builtin_bit_cast(short8v, u);
}

// ---------------------------------------------------------------------------
// K0: Uh = h@Uw.T+Ub (row-major); VhT,AhT = transposed [b][n][i] copies;
// Ah row-major (for pass 1); BhC = h@Bw.T + Bb + Cb (base prefold).
// Blocks 100..115 convert Cw->bf16.
// ---------------------------------------------------------------------------
__global__ __launch_bounds__(256) void prelin_kernel(
    const float* __restrict__ h,
    const float* __restrict__ Uw, const float* __restrict__ Ub,
    const float* __restrict__ Vw, const float* __restrict__ Vb,
    const float* __restrict__ Aw, const float* __restrict__ Ab,
    const float* __restrict__ Bw, const float* __restrict__ Bb,
    const float* __restrict__ Cw, const float* __restrict__ Cb,
    float* __restrict__ Uh, float* __restrict__ VhT,
    float* __restrict__ Ah, float* __restrict__ AhT,
    float* __restrict__ BhC,
    unsigned short* __restrict__ Cwbf) {
  const int tid = threadIdx.x;
  if (blockIdx.x >= 100) {
    int g = (blockIdx.x - 100) * 1024 + tid * 4;
    float4v v = *(const float4v*)(Cw + g);
    short4v s;
    s.x = (short)f2b(v.x); s.y = (short)f2b(v.y);
    s.z = (short)f2b(v.z); s.w = (short)f2b(v.w);
    *(short4v*)(Cwbf + g) = s;
    return;
  }
  const int r0 = blockIdx.x * 16;
  __shared__ float hs[16][128];
  for (int k = 0; k < 2; k++) {
    int g = k * 256 + tid;
    int row = g >> 5, col4 = g & 31;
    *(float4v*)&hs[row][col4 * 4] =
        *(const float4v*)(h + (size_t)(r0 + row) * D_ + col4 * 4);
  }
  __syncthreads();
  const int c0 = tid, c1 = tid + 256;
  const float* w0 = (c0 < 128) ? (Uw + c0 * 128) : (Vw + (c0 - 128) * 128);
  const float  b0 = (c0 < 128) ? Ub[c0] : Vb[c0 - 128];
  const float* w1 = (c1 < 384) ? (Aw + (c1 - 256) * 128) : (Bw + (c1 - 384) * 128);
  const float  b1 = (c1 < 384) ? Ab[c1 - 256] : (Bb[c1 - 384] + Cb[c1 - 384]);
  float acc0[16], acc1[16];
#pragma unroll
  for (int r = 0; r < 16; r++) { acc0[r] = 0.f; acc1[r] = 0.f; }
  for (int k = 0; k < 128; k += 4) {
    float4v w0v = *(const float4v*)(w0 + k);
    float4v w1v = *(const float4v*)(w1 + k);
#pragma unroll
    for (int r = 0; r < 16; r++) {
      float4v hv = *(const float4v*)&hs[r][k];
      acc0[r] = fmaf(hv.x, w0v.x, fmaf(hv.y, w0v.y, fmaf(hv.z, w0v.z, fmaf(hv.w, w0v.w, acc0[r]))));
      acc1[r] = fmaf(hv.x, w1v.x, fmaf(hv.y, w1v.y, fmaf(hv.z, w1v.z, fmaf(hv.w, w1v.w, acc1[r]))));
    }
  }
  const int cc0 = c0 & 127;
  const int cc1 = (c1 - 256) & 127;
#pragma unroll
  for (int r = 0; r < 16; r++) {
    const int g = r0 + r;
    const int bb = g / 200;
    const int ii = g - bb * 200;
    float v0 = acc0[r] + b0;
    if (c0 < 128) Uh[(size_t)g * D_ + cc0] = v0;
    else          VhT[((size_t)bb * D_ + cc0) * N_ + ii] = v0;
    float v1 = acc1[r] + b1;
    if (c1 < 384) {
      Ah[(size_t)g * D_ + cc1] = v1;
      AhT[((size_t)bb * D_ + cc1) * N_ + ii] = v1;
    } else {
      BhC[(size_t)g * D_ + cc1] = v1;
    }
  }
}

// ---------------------------------------------------------------------------
// K1/K4: per-(b,i) block, barrier-free K-loop, 32KB swizzled Cw LDS.
// MODE 0: D = e.Cw^T (lane: n=t*16+c, j=j0+wz*16+q*4+r). float4 AhT/VhT
//         epilogue loads, sigmoid-gate agg + BN sums (per-thread regs).
// MODE 1: D = Cw.e^T (lane: j=wz*16+c, n=t*16+q*4+r). float4 epilogue+store.
//         blocks >= BN_ run the fused hpath.
// ---------------------------------------------------------------------------
template <int MODE>
__global__ __launch_bounds__(256, 5) void gemm_pass(
    const float* __restrict__ e, const unsigned short* __restrict__ Cwbf,
    const float* __restrict__ BhC, const float* __restrict__ Ah,
    const float* __restrict__ AhT, const float* __restrict__ VhT,
    float* __restrict__ agg, float* __restrict__ psum, float* __restrict__ psumsq,
    const float* __restrict__ scale_e, const float* __restrict__ shift_e,
    float* __restrict__ e_out,
    const float* __restrict__ hin, const float* __restrict__ Uh,
    const float* __restrict__ scale_h, const float* __restrict__ shift_h,
    float* __restrict__ h_out) {
  const int tid = threadIdx.x;

  if (MODE == 1 && blockIdx.x >= BN_) {   // fused hpath tail (200 blocks)
    const int idx = (blockIdx.x - BN_) * 256 + tid;
    float4v u = ((const float4v*)Uh)[idx];
    float4v a = ((const float4v*)agg)[idx];
    float4v hv = ((const float4v*)hin)[idx];
    float4v sc = ((const float4v*)scale_h)[idx & 31];
    float4v sh = ((const float4v*)shift_h)[idx & 31];
    float4v o;
#pragma unroll
    for (int l = 0; l < 4; l++) {
      float y = fmaxf(fmaf(u[l] + a[l], sc[l], sh[l]), 0.f);
      o[l] = hv[l] + y;
    }
    ((float4v*)h_out)[idx] = o;
    return;
  }

  const int blk = blockIdx.x;
  const int b = blk / N_;
  const int lane = tid & 63, wz = tid >> 6;
  const int c = lane & 15, q = lane >> 4;

  // exactly 32 KiB -> 5 blocks/CU. XOR-swizzled 16B units: col16 ^= (row&7).
  __shared__ __align__(16) unsigned short Bs[128 * 128];

  const uint4v* bsrc = (const uint4v*)Cwbf;
#pragma unroll
  for (int k2 = 0; k2 < 8; k2++) {
    int g = k2 * 256 + tid;
    int row = g >> 4;
    int col16 = (g & 15) ^ (row & 7);
    *(uint4v*)&Bs[row * 128 + col16 * 8] = bsrc[g];
  }

  // per-lane base = Cb + Bh (prefolded): n = t*16+c (MODE0 scalar layout)
  float bsev[8];
  if (MODE == 0) {
#pragma unroll
    for (int t = 0; t < 8; t++) bsev[t] = BhC[(size_t)blk * D_ + t * 16 + c];
  }
  __syncthreads();   // the ONLY barrier before the K-loop

  const float* erow = e + (size_t)blk * N_ * D_;
  const float* AhB = Ah + (size_t)b * N_ * D_;
  const float* AhTb = AhT + (size_t)b * D_ * N_;
  const float* VhTb = VhT + (size_t)b * D_ * N_;
  const float* BhCrow = BhC + (size_t)blk * D_;

  float aggv[8], sumv[8], sqv[8];
  if (MODE == 0) {
#pragma unroll
    for (int t = 0; t < 8; t++) { aggv[t] = 0.f; sumv[t] = 0.f; sqv[t] = 0.f; }
  }

  const int sw = c & 7;   // Bs row swizzle key (row = t*16+c -> row&7 == c&7)

  float4v ef[8];
  {
    const int j = wz * 16 + c;
    const float* p = erow + (size_t)j * D_ + q * 8;
    const bool ok = (j < N_);
#pragma unroll
    for (int l = 0; l < 4; l++) {
      ef[2 * l]     = ok ? *(const float4v*)(p + l * 32)     : (float4v){0.f,0.f,0.f,0.f};
      ef[2 * l + 1] = ok ? *(const float4v*)(p + l * 32 + 4) : (float4v){0.f,0.f,0.f,0.f};
    }
  }

#pragma unroll
  for (int jt = 0; jt < 4; jt++) {
    const int j0 = jt * 64;
    // convert current tile fragments fp32->bf16 (packed cvt)
    short8v av[4];
#pragma unroll
    for (int l = 0; l < 4; l++) av[l] = cvt_bf16x8(ef[2 * l], ef[2 * l + 1]);

    // prefetch next tile while this tile computes
    if (jt < 3) {
      const int j = (jt + 1) * 64 + wz * 16 + c;
      const float* p = erow + (size_t)j * D_ + q * 8;
      const bool ok = (j < N_);
#pragma unroll
      for (int l = 0; l < 4; l++) {
        ef[2 * l]     = ok ? *(const float4v*)(p + l * 32)     : (float4v){0.f,0.f,0.f,0.f};
        ef[2 * l + 1] = ok ? *(const float4v*)(p + l * 32 + 4) : (float4v){0.f,0.f,0.f,0.f};
      }
    }

    float4v acc[8];
#pragma unroll
    for (int t = 0; t < 8; t++) acc[t] = (float4v){0.f, 0.f, 0.f, 0.f};
#pragma unroll
    for (int t = 0; t < 8; t++) {
      const unsigned short* brow = &Bs[(t * 16 + c) * 128];
#pragma unroll
      for (int l = 0; l < 4; l++) {
        short8v cw = *(const short8v*)(brow + (((q | (l << 2)) ^ sw) << 3));
        if (MODE == 0)
          acc[t] = __builtin_amdgcn_mfma_f32_16x16x32_bf16(av[l], cw, acc[t], 0, 0, 0);
        else
          acc[t] = __builtin_amdgcn_mfma_f32_16x16x32_bf16(cw, av[l], acc[t], 0, 0, 0);
      }
    }

    if (MODE == 0) {
      // D layout: n = t*16+c, j = j0 + wz*16 + q*4 + r  -> float4 over r
      const int jb = j0 + wz * 16 + q * 4;
      if (jb < N_) {                      // jb%4==0, N_%4==0: whole quad valid
        const float* pA = AhTb + (size_t)c * N_ + jb;
        const float* pV = VhTb + (size_t)c * N_ + jb;
#pragma unroll
        for (int t = 0; t < 8; t++) {
          float4v ah4 = *(const float4v*)(pA + (size_t)t * 16 * N_);
          float4v vh4 = *(const float4v*)(pV + (size_t)t * 16 * N_);
          const float bse = bsev[t];
          float ag = aggv[t], sm = sumv[t], sq2 = sqv[t];
#pragma unroll
          for (int r = 0; r < 4; r++) {
            float x = acc[t][r] + bse + ah4[r];
            float g = __builtin_amdgcn_rcpf(1.0f + __expf(-x));
            ag = fmaf(g, vh4[r], ag);
            sm += x;
            sq2 = fmaf(x, x, sq2);
          }
          aggv[t] = ag; sumv[t] = sm; sqv[t] = sq2;
        }
      }
    } else {
      // D layout: j = j0 + wz*16 + c (fixed), n = t*16 + q*4 + r  -> float4
      const int j = j0 + wz * 16 + c;
      if (j < N_) {
        const size_t rowoff = (size_t)blk * N_ * D_ + (size_t)j * D_;
#pragma unroll
        for (int t = 0; t < 8; t++) {
          const int n4 = t * 16 + q * 4;
          float4v ah = *(const float4v*)(AhB + (size_t)j * D_ + n4);
          float4v bs4 = *(const float4v*)(BhCrow + n4);
          float4v sc4 = *(const float4v*)(scale_e + n4);
          float4v sh4 = *(const float4v*)(shift_e + n4);
          float4v ein = *(const float4v*)(e + rowoff + n4);
          float4v o;
#pragma unroll
          for (int r = 0; r < 4; r++) {
            float x = acc[t][r] + bs4[r] + ah[r];
            float y = fmaxf(fmaf(x, sc4[r], sh4[r]), 0.f);
            o[r] = ein[r] + y;
          }
          *(float4v*)(e_out + rowoff + n4) = o;
        }
      }
    }
  }

  if (MODE == 0) {
    __syncthreads();                 // all MFMA reads of Bs done; reuse as f32
    float* red = (float*)Bs;         // [3][4][128]
#pragma unroll
    for (int t = 0; t < 8; t++) {
      float a = aggv[t], s = sumv[t], sq2 = sqv[t];
      a += __shfl_xor(a, 16); a += __shfl_xor(a, 32);
      s += __shfl_xor(s, 16); s += __shfl_xor(s, 32);
      sq2 += __shfl_xor(sq2, 16); sq2 += __shfl_xor(sq2, 32);
      if (q == 0) {
        red[(0 * 4 + wz) * 128 + t * 16 + c] = a;
        red[(1 * 4 + wz) * 128 + t * 16 + c] = s;
        red[(2 * 4 + wz) * 128 + t * 16 + c] = sq2;
      }
    }
    __syncthreads();
    if (tid < 128) {
      float a = 0.f, s = 0.f, sq2 = 0.f;
#pragma unroll
      for (int w = 0; w < 4; w++) {
        a += red[(0 * 4 + w) * 128 + tid];
        s += red[(1 * 4 + w) * 128 + tid];
        sq2 += red[(2 * 4 + w) * 128 + tid];
      }
      agg[(size_t)blk * D_ + tid] = a;
      psum[(size_t)blk * D_ + tid] = s;
      psumsq[(size_t)blk * D_ + tid] = sq2;
    }
  }
}

// ---------------------------------------------------------------------------
// K2a: coalesced partial reduction of BN stats (100 blocks x 16 rows)
// ---------------------------------------------------------------------------
__global__ __launch_bounds__(256) void stats_part(
    const float* __restrict__ psum, const float* __restrict__ psumsq,
    const float* __restrict__ Uh, const float* __restrict__ agg,
    float* __restrict__ partial) {
  const int t = threadIdx.x, blk = blockIdx.x;
  const int cg = t & 31, rs = t >> 5;
  float4v ps = {0,0,0,0}, pq = {0,0,0,0}, hs = {0,0,0,0}, hq = {0,0,0,0};
#pragma unroll
  for (int p = 0; p < 2; p++) {
    const int row = blk * 16 + p * 8 + rs;
    const size_t off = (size_t)row * D_ + cg * 4;
    float4v a = *(const float4v*)(psum + off);
    float4v bq = *(const float4v*)(psumsq + off);
    float4v u = *(const float4v*)(Uh + off);
    float4v g = *(const float4v*)(agg + off);
    ps += a; pq += bq;
    float4v hv = u + g;
    hs += hv; hq += hv * hv;
  }
  __shared__ float4v red[4][8][32];
  red[0][rs][cg] = ps; red[1][rs][cg] = pq; red[2][rs][cg] = hs; red[3][rs][cg] = hq;
  __syncthreads();
  if (t < 128) {
    const int s = t >> 5, g = t & 31;
    float4v acc = red[s][0][g];
#pragma unroll
    for (int r = 1; r < 8; r++) acc += red[s][r][g];
    *(float4v*)(partial + (size_t)blk * 512 + s * 128 + g * 4) = acc;
  }
}

// ---------------------------------------------------------------------------
// K2b: final stats -> scale/shift (1 block, 256 threads, e/h split)
// ---------------------------------------------------------------------------
__global__ __launch_bounds__(256) void stats_final(
    const float* __restrict__ partial,
    const float* __restrict__ gamma_h, const float* __restrict__ beta_h,
    const float* __restrict__ gamma_e, const float* __restrict__ beta_e,
    float* __restrict__ scale_e, float* __restrict__ shift_e,
    float* __restrict__ scale_h, float* __restrict__ shift_h) {
  const int t = threadIdx.x;
  const int n = t & 127;
  if (t < 128) {
    float s = 0.f, sq = 0.f;
    for (int p = 0; p < 100; p++) {
      const float* base = partial + (size_t)p * 512;
      s += base[n]; sq += base[128 + n];
    }
    const float Me = 8.f * 200.f * 200.f;
    float mean = s / Me;
    float var = sq / Me - mean * mean;
    float sce = gamma_e[n] * rsqrtf(var + 1e-5f);
    scale_e[n] = sce; shift_e[n] = beta_e[n] - mean * sce;
  } else {
    float hs = 0.f, hq = 0.f;
    for (int p = 0; p < 100; p++) {
      const float* base = partial + (size_t)p * 512;
      hs += base[256 + n]; hq += base[384 + n];
    }
    const float Mh = (float)BN_;
    float mh = hs / Mh;
    float vh = hq / Mh - mh * mh;
    float sch = gamma_h[n] * rsqrtf(vh + 1e-5f);
    scale_h[n] = sch; shift_h[n] = beta_h[n] - mh * sch;
  }
}

// ---------------------------------------------------------------------------
extern "C" void kernel_launch(void* const* d_in, const int* in_sizes, int n_in,
                              void* d_out, int out_size, void* d_ws, size_t ws_size,
                              hipStream_t stream) {
  const float* h  = (const float*)d_in[0];
  const float* e  = (const float*)d_in[1];
  const float* Uw = (const float*)d_in[2];  const float* Ub = (const float*)d_in[3];
  const float* Vw = (const float*)d_in[4];  const float* Vb = (const float*)d_in[5];
  const float* Aw = (const float*)d_in[6];  const float* Ab = (const float*)d_in[7];
  const float* Bw = (const float*)d_in[8];  const float* Bb = (const float*)d_in[9];
  const float* Cw = (const float*)d_in[10]; const float* Cb = (const float*)d_in[11];
  const float* gamma_h = (const float*)d_in[12]; const float* beta_h = (const float*)d_in[13];
  const float* gamma_e = (const float*)d_in[14]; const float* beta_e = (const float*)d_in[15];

  float* ws = (float*)d_ws;
  float* Uh   = ws + 0;
  float* VhT  = ws + (size_t)HN_;
  float* Ah   = ws + (size_t)HN_ * 2;
  float* BhC  = ws + (size_t)HN_ * 3;
  float* agg  = ws + (size_t)HN_ * 4;
  float* psum = ws + (size_t)HN_ * 5;
  float* psumsq = ws + (size_t)HN_ * 6;
  float* AhT  = ws + (size_t)HN_ * 7;
  float* scale_e = ws + (size_t)HN_ * 8;
  float* shift_e = scale_e + 128;
  float* scale_h = scale_e + 256;
  float* shift_h = scale_e + 384;
  unsigned short* Cwbf = (unsigned short*)(scale_e + 512);
  float* partial = scale_e + 512 + 8192;   // 100*512 floats

  float* h_out = (float*)d_out;
  float* e_out = (float*)d_out + HN_;

  prelin_kernel<<<116, 256, 0, stream>>>(h, Uw, Ub, Vw, Vb, Aw, Ab, Bw, Bb, Cw, Cb,
                                         Uh, VhT, Ah, AhT, BhC, Cwbf);
  gemm_pass<0><<<BN_, 256, 0, stream>>>(e, Cwbf, BhC, Ah, AhT, VhT,
                                        agg, psum, psumsq,
                                        nullptr, nullptr, nullptr,
                                        nullptr, nullptr, nullptr, nullptr, nullptr);
  stats_part<<<100, 256, 0, stream>>>(psum, psumsq, Uh, agg, partial);
  stats_final<<<1, 256, 0, stream>>>(partial, gamma_h, beta_h, gamma_e, beta_e,
                                     scale_e, shift_e, scale_h, shift_h);
  gemm_pass<1><<<BN_ + 200, 256, 0, stream>>>(e, Cwbf, BhC, Ah, AhT, VhT,
                                              agg, psum, psumsq,
                                              scale_e, shift_e, e_out,
                                              h, Uh, scale_h, shift_h, h_out);
}

// Round 2
// 462.513 us; speedup vs baseline: 1.3085x; 1.3085x over previous
//
#include <hip/hip_runtime.h>

// GNNLayer: B=8, N=200, D=128, fp32 I/O. Recompute-Ce two-pass, bf16 MFMA.
// R4: == R3 but launch_bounds reverted (256,5)->(256,2). The (256,5) cap
// forced VGPR 48 -> scratch spills (+92MB write amplification, MODE1
// 118->196us). Keep: transposed AhT/VhT float4 epilogue, v_cvt_pk_bf16_f32,
// 32KB swizzled Bs, prefolded BhC, fused hpath, split stats_final.

#define B_ 8
#define N_ 200
#define D_ 128
#define BN_ (B_*N_)      // 1600
#define HN_ (BN_*D_)     // 204800

typedef __attribute__((ext_vector_type(8))) short short8v;
typedef __attribute__((ext_vector_type(4))) short short4v;
typedef __attribute__((ext_vector_type(4))) float float4v;
typedef __attribute__((ext_vector_type(4))) unsigned int uint4v;

__device__ __forceinline__ unsigned short f2b(float f) {
  unsigned u = __float_as_uint(f);
  u += 0x7FFFu + ((u >> 16) & 1u);
  return (unsigned short)(u >> 16);
}

// packed fp32->bf16 (RNE, identical to f2b) — 4 instrs for 8 elements
__device__ __forceinline__ short8v cvt_bf16x8(float4v lo, float4v hi) {
  unsigned int r0, r1, r2, r3;
  asm("v_cvt_pk_bf16_f32 %0, %1, %2" : "=v"(r0) : "v"(lo.x), "v"(lo.y));
  asm("v_cvt_pk_bf16_f32 %0, %1, %2" : "=v"(r1) : "v"(lo.z), "v"(lo.w));
  asm("v_cvt_pk_bf16_f32 %0, %1, %2" : "=v"(r2) : "v"(hi.x), "v"(hi.y));
  asm("v_cvt_pk_bf16_f32 %0, %1, %2" : "=v"(r3) : "v"(hi.z), "v"(hi.w));
  uint4v u; u.x = r0; u.y = r1; u.z = r2; u.w = r3;
  return __builtin_bit_cast(short8v, u);
}

// ---------------------------------------------------------------------------
// K0: Uh = h@Uw.T+Ub (row-major); VhT,AhT = transposed [b][n][i] copies;
// Ah row-major (for pass 1); BhC = h@Bw.T + Bb + Cb (base prefold).
// Blocks 100..115 convert Cw->bf16.
// ---------------------------------------------------------------------------
__global__ __launch_bounds__(256) void prelin_kernel(
    const float* __restrict__ h,
    const float* __restrict__ Uw, const float* __restrict__ Ub,
    const float* __restrict__ Vw, const float* __restrict__ Vb,
    const float* __restrict__ Aw, const float* __restrict__ Ab,
    const float* __restrict__ Bw, const float* __restrict__ Bb,
    const float* __restrict__ Cw, const float* __restrict__ Cb,
    float* __restrict__ Uh, float* __restrict__ VhT,
    float* __restrict__ Ah, float* __restrict__ AhT,
    float* __restrict__ BhC,
    unsigned short* __restrict__ Cwbf) {
  const int tid = threadIdx.x;
  if (blockIdx.x >= 100) {
    int g = (blockIdx.x - 100) * 1024 + tid * 4;
    float4v v = *(const float4v*)(Cw + g);
    short4v s;
    s.x = (short)f2b(v.x); s.y = (short)f2b(v.y);
    s.z = (short)f2b(v.z); s.w = (short)f2b(v.w);
    *(short4v*)(Cwbf + g) = s;
    return;
  }
  const int r0 = blockIdx.x * 16;
  __shared__ float hs[16][128];
  for (int k = 0; k < 2; k++) {
    int g = k * 256 + tid;
    int row = g >> 5, col4 = g & 31;
    *(float4v*)&hs[row][col4 * 4] =
        *(const float4v*)(h + (size_t)(r0 + row) * D_ + col4 * 4);
  }
  __syncthreads();
  const int c0 = tid, c1 = tid + 256;
  const float* w0 = (c0 < 128) ? (Uw + c0 * 128) : (Vw + (c0 - 128) * 128);
  const float  b0 = (c0 < 128) ? Ub[c0] : Vb[c0 - 128];
  const float* w1 = (c1 < 384) ? (Aw + (c1 - 256) * 128) : (Bw + (c1 - 384) * 128);
  const float  b1 = (c1 < 384) ? Ab[c1 - 256] : (Bb[c1 - 384] + Cb[c1 - 384]);
  float acc0[16], acc1[16];
#pragma unroll
  for (int r = 0; r < 16; r++) { acc0[r] = 0.f; acc1[r] = 0.f; }
  for (int k = 0; k < 128; k += 4) {
    float4v w0v = *(const float4v*)(w0 + k);
    float4v w1v = *(const float4v*)(w1 + k);
#pragma unroll
    for (int r = 0; r < 16; r++) {
      float4v hv = *(const float4v*)&hs[r][k];
      acc0[r] = fmaf(hv.x, w0v.x, fmaf(hv.y, w0v.y, fmaf(hv.z, w0v.z, fmaf(hv.w, w0v.w, acc0[r]))));
      acc1[r] = fmaf(hv.x, w1v.x, fmaf(hv.y, w1v.y, fmaf(hv.z, w1v.z, fmaf(hv.w, w1v.w, acc1[r]))));
    }
  }
  const int cc0 = c0 & 127;
  const int cc1 = (c1 - 256) & 127;
#pragma unroll
  for (int r = 0; r < 16; r++) {
    const int g = r0 + r;
    const int bb = g / 200;
    const int ii = g - bb * 200;
    float v0 = acc0[r] + b0;
    if (c0 < 128) Uh[(size_t)g * D_ + cc0] = v0;
    else          VhT[((size_t)bb * D_ + cc0) * N_ + ii] = v0;
    float v1 = acc1[r] + b1;
    if (c1 < 384) {
      Ah[(size_t)g * D_ + cc1] = v1;
      AhT[((size_t)bb * D_ + cc1) * N_ + ii] = v1;
    } else {
      BhC[(size_t)g * D_ + cc1] = v1;
    }
  }
}

// ---------------------------------------------------------------------------
// K1/K4: per-(b,i) block, barrier-free K-loop, 32KB swizzled Cw LDS.
// MODE 0: D = e.Cw^T (lane: n=t*16+c, j=j0+wz*16+q*4+r). float4 AhT/VhT
//         epilogue loads, sigmoid-gate agg + BN sums (per-thread regs).
// MODE 1: D = Cw.e^T (lane: j=wz*16+c, n=t*16+q*4+r). float4 epilogue+store.
//         blocks >= BN_ run the fused hpath.
// ---------------------------------------------------------------------------
template <int MODE>
__global__ __launch_bounds__(256, 2) void gemm_pass(
    const float* __restrict__ e, const unsigned short* __restrict__ Cwbf,
    const float* __restrict__ BhC, const float* __restrict__ Ah,
    const float* __restrict__ AhT, const float* __restrict__ VhT,
    float* __restrict__ agg, float* __restrict__ psum, float* __restrict__ psumsq,
    const float* __restrict__ scale_e, const float* __restrict__ shift_e,
    float* __restrict__ e_out,
    const float* __restrict__ hin, const float* __restrict__ Uh,
    const float* __restrict__ scale_h, const float* __restrict__ shift_h,
    float* __restrict__ h_out) {
  const int tid = threadIdx.x;

  if (MODE == 1 && blockIdx.x >= BN_) {   // fused hpath tail (200 blocks)
    const int idx = (blockIdx.x - BN_) * 256 + tid;
    float4v u = ((const float4v*)Uh)[idx];
    float4v a = ((const float4v*)agg)[idx];
    float4v hv = ((const float4v*)hin)[idx];
    float4v sc = ((const float4v*)scale_h)[idx & 31];
    float4v sh = ((const float4v*)shift_h)[idx & 31];
    float4v o;
#pragma unroll
    for (int l = 0; l < 4; l++) {
      float y = fmaxf(fmaf(u[l] + a[l], sc[l], sh[l]), 0.f);
      o[l] = hv[l] + y;
    }
    ((float4v*)h_out)[idx] = o;
    return;
  }

  const int blk = blockIdx.x;
  const int b = blk / N_;
  const int lane = tid & 63, wz = tid >> 6;
  const int c = lane & 15, q = lane >> 4;

  // exactly 32 KiB. XOR-swizzled 16B units: col16 ^= (row&7).
  __shared__ __align__(16) unsigned short Bs[128 * 128];

  const uint4v* bsrc = (const uint4v*)Cwbf;
#pragma unroll
  for (int k2 = 0; k2 < 8; k2++) {
    int g = k2 * 256 + tid;
    int row = g >> 4;
    int col16 = (g & 15) ^ (row & 7);
    *(uint4v*)&Bs[row * 128 + col16 * 8] = bsrc[g];
  }

  // per-lane base = Cb + Bh (prefolded): n = t*16+c (MODE0 scalar layout)
  float bsev[8];
  if (MODE == 0) {
#pragma unroll
    for (int t = 0; t < 8; t++) bsev[t] = BhC[(size_t)blk * D_ + t * 16 + c];
  }
  __syncthreads();   // the ONLY barrier before the K-loop

  const float* erow = e + (size_t)blk * N_ * D_;
  const float* AhB = Ah + (size_t)b * N_ * D_;
  const float* AhTb = AhT + (size_t)b * D_ * N_;
  const float* VhTb = VhT + (size_t)b * D_ * N_;
  const float* BhCrow = BhC + (size_t)blk * D_;

  float aggv[8], sumv[8], sqv[8];
  if (MODE == 0) {
#pragma unroll
    for (int t = 0; t < 8; t++) { aggv[t] = 0.f; sumv[t] = 0.f; sqv[t] = 0.f; }
  }

  const int sw = c & 7;   // Bs row swizzle key (row = t*16+c -> row&7 == c&7)

  float4v ef[8];
  {
    const int j = wz * 16 + c;
    const float* p = erow + (size_t)j * D_ + q * 8;
    const bool ok = (j < N_);
#pragma unroll
    for (int l = 0; l < 4; l++) {
      ef[2 * l]     = ok ? *(const float4v*)(p + l * 32)     : (float4v){0.f,0.f,0.f,0.f};
      ef[2 * l + 1] = ok ? *(const float4v*)(p + l * 32 + 4) : (float4v){0.f,0.f,0.f,0.f};
    }
  }

#pragma unroll
  for (int jt = 0; jt < 4; jt++) {
    const int j0 = jt * 64;
    // convert current tile fragments fp32->bf16 (packed cvt)
    short8v av[4];
#pragma unroll
    for (int l = 0; l < 4; l++) av[l] = cvt_bf16x8(ef[2 * l], ef[2 * l + 1]);

    // prefetch next tile while this tile computes
    if (jt < 3) {
      const int j = (jt + 1) * 64 + wz * 16 + c;
      const float* p = erow + (size_t)j * D_ + q * 8;
      const bool ok = (j < N_);
#pragma unroll
      for (int l = 0; l < 4; l++) {
        ef[2 * l]     = ok ? *(const float4v*)(p + l * 32)     : (float4v){0.f,0.f,0.f,0.f};
        ef[2 * l + 1] = ok ? *(const float4v*)(p + l * 32 + 4) : (float4v){0.f,0.f,0.f,0.f};
      }
    }

    float4v acc[8];
#pragma unroll
    for (int t = 0; t < 8; t++) acc[t] = (float4v){0.f, 0.f, 0.f, 0.f};
#pragma unroll
    for (int t = 0; t < 8; t++) {
      const unsigned short* brow = &Bs[(t * 16 + c) * 128];
#pragma unroll
      for (int l = 0; l < 4; l++) {
        short8v cw = *(const short8v*)(brow + (((q | (l << 2)) ^ sw) << 3));
        if (MODE == 0)
          acc[t] = __builtin_amdgcn_mfma_f32_16x16x32_bf16(av[l], cw, acc[t], 0, 0, 0);
        else
          acc[t] = __builtin_amdgcn_mfma_f32_16x16x32_bf16(cw, av[l], acc[t], 0, 0, 0);
      }
    }

    if (MODE == 0) {
      // D layout: n = t*16+c, j = j0 + wz*16 + q*4 + r  -> float4 over r
      const int jb = j0 + wz * 16 + q * 4;
      if (jb < N_) {                      // jb%4==0, N_%4==0: whole quad valid
        const float* pA = AhTb + (size_t)c * N_ + jb;
        const float* pV = VhTb + (size_t)c * N_ + jb;
#pragma unroll
        for (int t = 0; t < 8; t++) {
          float4v ah4 = *(const float4v*)(pA + (size_t)t * 16 * N_);
          float4v vh4 = *(const float4v*)(pV + (size_t)t * 16 * N_);
          const float bse = bsev[t];
          float ag = aggv[t], sm = sumv[t], sq2 = sqv[t];
#pragma unroll
          for (int r = 0; r < 4; r++) {
            float x = acc[t][r] + bse + ah4[r];
            float g = __builtin_amdgcn_rcpf(1.0f + __expf(-x));
            ag = fmaf(g, vh4[r], ag);
            sm += x;
            sq2 = fmaf(x, x, sq2);
          }
          aggv[t] = ag; sumv[t] = sm; sqv[t] = sq2;
        }
      }
    } else {
      // D layout: j = j0 + wz*16 + c (fixed), n = t*16 + q*4 + r  -> float4
      const int j = j0 + wz * 16 + c;
      if (j < N_) {
        const size_t rowoff = (size_t)blk * N_ * D_ + (size_t)j * D_;
#pragma unroll
        for (int t = 0; t < 8; t++) {
          const int n4 = t * 16 + q * 4;
          float4v ah = *(const float4v*)(AhB + (size_t)j * D_ + n4);
          float4v bs4 = *(const float4v*)(BhCrow + n4);
          float4v sc4 = *(const float4v*)(scale_e + n4);
          float4v sh4 = *(const float4v*)(shift_e + n4);
          float4v ein = *(const float4v*)(e + rowoff + n4);
          float4v o;
#pragma unroll
          for (int r = 0; r < 4; r++) {
            float x = acc[t][r] + bs4[r] + ah[r];
            float y = fmaxf(fmaf(x, sc4[r], sh4[r]), 0.f);
            o[r] = ein[r] + y;
          }
          *(float4v*)(e_out + rowoff + n4) = o;
        }
      }
    }
  }

  if (MODE == 0) {
    __syncthreads();                 // all MFMA reads of Bs done; reuse as f32
    float* red = (float*)Bs;         // [3][4][128]
#pragma unroll
    for (int t = 0; t < 8; t++) {
      float a = aggv[t], s = sumv[t], sq2 = sqv[t];
      a += __shfl_xor(a, 16); a += __shfl_xor(a, 32);
      s += __shfl_xor(s, 16); s += __shfl_xor(s, 32);
      sq2 += __shfl_xor(sq2, 16); sq2 += __shfl_xor(sq2, 32);
      if (q == 0) {
        red[(0 * 4 + wz) * 128 + t * 16 + c] = a;
        red[(1 * 4 + wz) * 128 + t * 16 + c] = s;
        red[(2 * 4 + wz) * 128 + t * 16 + c] = sq2;
      }
    }
    __syncthreads();
    if (tid < 128) {
      float a = 0.f, s = 0.f, sq2 = 0.f;
#pragma unroll
      for (int w = 0; w < 4; w++) {
        a += red[(0 * 4 + w) * 128 + tid];
        s += red[(1 * 4 + w) * 128 + tid];
        sq2 += red[(2 * 4 + w) * 128 + tid];
      }
      agg[(size_t)blk * D_ + tid] = a;
      psum[(size_t)blk * D_ + tid] = s;
      psumsq[(size_t)blk * D_ + tid] = sq2;
    }
  }
}

// ---------------------------------------------------------------------------
// K2a: coalesced partial reduction of BN stats (100 blocks x 16 rows)
// ---------------------------------------------------------------------------
__global__ __launch_bounds__(256) void stats_part(
    const float* __restrict__ psum, const float* __restrict__ psumsq,
    const float* __restrict__ Uh, const float* __restrict__ agg,
    float* __restrict__ partial) {
  const int t = threadIdx.x, blk = blockIdx.x;
  const int cg = t & 31, rs = t >> 5;
  float4v ps = {0,0,0,0}, pq = {0,0,0,0}, hs = {0,0,0,0}, hq = {0,0,0,0};
#pragma unroll
  for (int p = 0; p < 2; p++) {
    const int row = blk * 16 + p * 8 + rs;
    const size_t off = (size_t)row * D_ + cg * 4;
    float4v a = *(const float4v*)(psum + off);
    float4v bq = *(const float4v*)(psumsq + off);
    float4v u = *(const float4v*)(Uh + off);
    float4v g = *(const float4v*)(agg + off);
    ps += a; pq += bq;
    float4v hv = u + g;
    hs += hv; hq += hv * hv;
  }
  __shared__ float4v red[4][8][32];
  red[0][rs][cg] = ps; red[1][rs][cg] = pq; red[2][rs][cg] = hs; red[3][rs][cg] = hq;
  __syncthreads();
  if (t < 128) {
    const int s = t >> 5, g = t & 31;
    float4v acc = red[s][0][g];
#pragma unroll
    for (int r = 1; r < 8; r++) acc += red[s][r][g];
    *(float4v*)(partial + (size_t)blk * 512 + s * 128 + g * 4) = acc;
  }
}

// ---------------------------------------------------------------------------
// K2b: final stats -> scale/shift (1 block, 256 threads, e/h split)
// ---------------------------------------------------------------------------
__global__ __launch_bounds__(256) void stats_final(
    const float* __restrict__ partial,
    const float* __restrict__ gamma_h, const float* __restrict__ beta_h,
    const float* __restrict__ gamma_e, const float* __restrict__ beta_e,
    float* __restrict__ scale_e, float* __restrict__ shift_e,
    float* __restrict__ scale_h, float* __restrict__ shift_h) {
  const int t = threadIdx.x;
  const int n = t & 127;
  if (t < 128) {
    float s = 0.f, sq = 0.f;
    for (int p = 0; p < 100; p++) {
      const float* base = partial + (size_t)p * 512;
      s += base[n]; sq += base[128 + n];
    }
    const float Me = 8.f * 200.f * 200.f;
    float mean = s / Me;
    float var = sq / Me - mean * mean;
    float sce = gamma_e[n] * rsqrtf(var + 1e-5f);
    scale_e[n] = sce; shift_e[n] = beta_e[n] - mean * sce;
  } else {
    float hs = 0.f, hq = 0.f;
    for (int p = 0; p < 100; p++) {
      const float* base = partial + (size_t)p * 512;
      hs += base[256 + n]; hq += base[384 + n];
    }
    const float Mh = (float)BN_;
    float mh = hs / Mh;
    float vh = hq / Mh - mh * mh;
    float sch = gamma_h[n] * rsqrtf(vh + 1e-5f);
    scale_h[n] = sch; shift_h[n] = beta_h[n] - mh * sch;
  }
}

// ---------------------------------------------------------------------------
extern "C" void kernel_launch(void* const* d_in, const int* in_sizes, int n_in,
                              void* d_out, int out_size, void* d_ws, size_t ws_size,
                              hipStream_t stream) {
  const float* h  = (const float*)d_in[0];
  const float* e  = (const float*)d_in[1];
  const float* Uw = (const float*)d_in[2];  const float* Ub = (const float*)d_in[3];
  const float* Vw = (const float*)d_in[4];  const float* Vb = (const float*)d_in[5];
  const float* Aw = (const float*)d_in[6];  const float* Ab = (const float*)d_in[7];
  const float* Bw = (const float*)d_in[8];  const float* Bb = (const float*)d_in[9];
  const float* Cw = (const float*)d_in[10]; const float* Cb = (const float*)d_in[11];
  const float* gamma_h = (const float*)d_in[12]; const float* beta_h = (const float*)d_in[13];
  const float* gamma_e = (const float*)d_in[14]; const float* beta_e = (const float*)d_in[15];

  float* ws = (float*)d_ws;
  float* Uh   = ws + 0;
  float* VhT  = ws + (size_t)HN_;
  float* Ah   = ws + (size_t)HN_ * 2;
  float* BhC  = ws + (size_t)HN_ * 3;
  float* agg  = ws + (size_t)HN_ * 4;
  float* psum = ws + (size_t)HN_ * 5;
  float* psumsq = ws + (size_t)HN_ * 6;
  float* AhT  = ws + (size_t)HN_ * 7;
  float* scale_e = ws + (size_t)HN_ * 8;
  float* shift_e = scale_e + 128;
  float* scale_h = scale_e + 256;
  float* shift_h = scale_e + 384;
  unsigned short* Cwbf = (unsigned short*)(scale_e + 512);
  float* partial = scale_e + 512 + 8192;   // 100*512 floats

  float* h_out = (float*)d_out;
  float* e_out = (float*)d_out + HN_;

  prelin_kernel<<<116, 256, 0, stream>>>(h, Uw, Ub, Vw, Vb, Aw, Ab, Bw, Bb, Cw, Cb,
                                         Uh, VhT, Ah, AhT, BhC, Cwbf);
  gemm_pass<0><<<BN_, 256, 0, stream>>>(e, Cwbf, BhC, Ah, AhT, VhT,
                                        agg, psum, psumsq,
                                        nullptr, nullptr, nullptr,
                                        nullptr, nullptr, nullptr, nullptr, nullptr);
  stats_part<<<100, 256, 0, stream>>>(psum, psumsq, Uh, agg, partial);
  stats_final<<<1, 256, 0, stream>>>(partial, gamma_h, beta_h, gamma_e, beta_e,
                                     scale_e, shift_e, scale_h, shift_h);
  gemm_pass<1><<<BN_ + 200, 256, 0, stream>>>(e, Cwbf, BhC, Ah, AhT, VhT,
                                              agg, psum, psumsq,
                                              scale_e, shift_e, e_out,
                                              h, Uh, scale_h, shift_h, h_out);
}